// Round 1
// baseline (740.400 us; speedup 1.0000x reference)
//
#include <hip/hip_runtime.h>

#define N_NODES 30000
#define F_INLEN 500
#define HID 16
#define OUTC 3
#define NEDGE 960000

// ---------------- K1: conv1 -> relu -> conv2 -> relu -> max over positions ----
// One block per node. y1 stored channel-major [16][504] (rows = pos+1, rows 0/501..503 zero)
// so conv2 reads contiguous float4 along positions.
__global__ __launch_bounds__(256, 4) void conv_fused(
    const float* __restrict__ x,
    const float* __restrict__ w1, const float* __restrict__ b1,
    const float* __restrict__ w2, const float* __restrict__ b2,
    float* __restrict__ h0, float* __restrict__ deg)
{
    __shared__ float xp[502];
    __shared__ float y1[16][504];
    __shared__ float wsm[768];
    __shared__ float red[16 * 17];
    const int tid  = threadIdx.x;
    const int node = blockIdx.x;

    for (int t = tid; t < 768; t += 256) wsm[t] = w2[t];
    if (tid == 0) { deg[node] = 1.0f; xp[0] = 0.f; xp[501] = 0.f; }
    if (tid < 125) {
        const float4 v = ((const float4*)(x + (long long)node * F_INLEN))[tid];
        xp[4 * tid + 1] = v.x; xp[4 * tid + 2] = v.y;
        xp[4 * tid + 3] = v.z; xp[4 * tid + 4] = v.w;
    }
    __syncthreads();

    // conv1 + relu: channel = tid&15, rows strided by 16
    const int ci = tid & 15;
    const float c10 = w1[ci * 3 + 0], c11 = w1[ci * 3 + 1], c12 = w1[ci * 3 + 2];
    const float c1b = b1[ci];
    for (int r = (tid >> 4); r < 504; r += 16) {
        float v = 0.f;
        if (r >= 1 && r <= 500)
            v = fmaxf(c1b + c10 * xp[r - 1] + c11 * xp[r] + c12 * xp[r + 1], 0.f);
        y1[ci][r] = v;
    }
    __syncthreads();

    // conv2 + relu + max. thread = (strip, o); strip handles positions 4*strip + 64*j
    const int o = tid & 15;
    const int strip = tid >> 4;
    float wv[16][3];
#pragma unroll
    for (int i = 0; i < 16; i++) {
        wv[i][0] = wsm[o * 48 + i * 3 + 0];
        wv[i][1] = wsm[o * 48 + i * 3 + 1];
        wv[i][2] = wsm[o * 48 + i * 3 + 2];
    }
    const float bo = b2[o];
    float mx = 0.f;  // relu folded into max: all relu'd values >= 0
    for (int j = 0; j < 8; j++) {
        const int p0 = 4 * strip + 64 * j;
        if (p0 >= F_INLEN) break;
        float s0 = bo, s1 = bo, s2 = bo, s3 = bo;
#pragma unroll
        for (int i = 0; i < 16; i++) {
            const float4 a  = *(const float4*)&y1[i][p0];
            const float4 bq = *(const float4*)&y1[i][p0 + 4];
            s0 = fmaf(wv[i][0], a.x, s0); s0 = fmaf(wv[i][1], a.y, s0); s0 = fmaf(wv[i][2], a.z, s0);
            s1 = fmaf(wv[i][0], a.y, s1); s1 = fmaf(wv[i][1], a.z, s1); s1 = fmaf(wv[i][2], a.w, s1);
            s2 = fmaf(wv[i][0], a.z, s2); s2 = fmaf(wv[i][1], a.w, s2); s2 = fmaf(wv[i][2], bq.x, s2);
            s3 = fmaf(wv[i][0], a.w, s3); s3 = fmaf(wv[i][1], bq.x, s3); s3 = fmaf(wv[i][2], bq.y, s3);
        }
        if (p0 + 0 < F_INLEN) mx = fmaxf(mx, s0);
        if (p0 + 1 < F_INLEN) mx = fmaxf(mx, s1);
        if (p0 + 2 < F_INLEN) mx = fmaxf(mx, s2);
        if (p0 + 3 < F_INLEN) mx = fmaxf(mx, s3);
    }
    red[strip * 17 + o] = mx;
    __syncthreads();
    if (tid < 16) {
        float m = 0.f;
#pragma unroll
        for (int s = 0; s < 16; s++) m = fmaxf(m, red[s * 17 + tid]);
        h0[node * HID + tid] = m;
    }
}

// ---------------- K2: in-degree (+1 self-loop seeded in K1) ------------------
__global__ void deg_kernel(const int* __restrict__ dst, float* __restrict__ deg)
{
    int e = blockIdx.x * 256 + threadIdx.x;
    if (e < NEDGE) atomicAdd(&deg[dst[e]], 1.0f);
}

// ---------------- K3: t1 = h0 @ W1; acc1 = self-loop term; dinv --------------
__global__ void gcn1_pre(const float* __restrict__ h0, const float* __restrict__ W1,
                         const float* __restrict__ deg, float* __restrict__ dinv,
                         float* __restrict__ t1, float* __restrict__ acc1)
{
    __shared__ float wsm[256];
    const int tid = threadIdx.x;
    wsm[tid] = W1[tid];
    __syncthreads();
    const int gid = blockIdx.x * 256 + tid;
    const int n = gid >> 4, o = gid & 15;
    if (n >= N_NODES) return;
    const float di = rsqrtf(deg[n]);
    if (o == 0) dinv[n] = di;
    float hrow[16];
    const float4* hr = (const float4*)(h0 + n * HID);
#pragma unroll
    for (int q = 0; q < 4; q++) *(float4*)&hrow[4 * q] = hr[q];
    float t = 0.f;
#pragma unroll
    for (int i = 0; i < 16; i++) t = fmaf(hrow[i], wsm[i * 16 + o], t);
    t1[gid] = t;
    acc1[gid] = t * di * di;
}

// ---------------- K4: edge scatter layer 1 (16 lanes per edge) ---------------
__global__ void scat1(const int* __restrict__ src, const int* __restrict__ dst,
                      const float* __restrict__ dinv, const float* __restrict__ t1,
                      float* __restrict__ acc1)
{
    const int idx = blockIdx.x * 256 + threadIdx.x;
    if (idx >= NEDGE * 16) return;
    const int e = idx >> 4, o = idx & 15;
    const int s = src[e], d = dst[e];
    const float nrm = dinv[s] * dinv[d];
    atomicAdd(&acc1[d * HID + o], t1[s * HID + o] * nrm);
}

// ---------------- K5: h1 = relu(acc1+b); t2 = h1 @ W2; acc2 self term --------
__global__ void gcn_mid(const float* __restrict__ acc1, const float* __restrict__ b1g,
                        const float* __restrict__ W2, const float* __restrict__ dinv,
                        float* __restrict__ t2, float* __restrict__ acc2)
{
    __shared__ float wsm[48];
    __shared__ float bsm[16];
    const int tid = threadIdx.x;
    if (tid < 48) wsm[tid] = W2[tid];
    if (tid < 16) bsm[tid] = b1g[tid];
    __syncthreads();
    const int n = blockIdx.x * 256 + tid;
    if (n >= N_NODES) return;
    float h[16];
    const float4* ar = (const float4*)(acc1 + n * HID);
#pragma unroll
    for (int q = 0; q < 4; q++) {
        float4 v = ar[q];
        h[4 * q + 0] = fmaxf(v.x + bsm[4 * q + 0], 0.f);
        h[4 * q + 1] = fmaxf(v.y + bsm[4 * q + 1], 0.f);
        h[4 * q + 2] = fmaxf(v.z + bsm[4 * q + 2], 0.f);
        h[4 * q + 3] = fmaxf(v.w + bsm[4 * q + 3], 0.f);
    }
    const float di = dinv[n];
    const float d2 = di * di;
#pragma unroll
    for (int j = 0; j < 3; j++) {
        float t = 0.f;
#pragma unroll
        for (int i = 0; i < 16; i++) t = fmaf(h[i], wsm[i * 3 + j], t);
        t2[n * 3 + j] = t;
        acc2[n * 3 + j] = t * d2;
    }
}

// ---------------- K6: edge scatter layer 2 -----------------------------------
__global__ void scat2(const int* __restrict__ src, const int* __restrict__ dst,
                      const float* __restrict__ dinv, const float* __restrict__ t2,
                      float* __restrict__ acc2)
{
    const int e = blockIdx.x * 256 + threadIdx.x;
    if (e >= NEDGE) return;
    const int s = src[e], d = dst[e];
    const float nrm = dinv[s] * dinv[d];
    atomicAdd(&acc2[d * 3 + 0], t2[s * 3 + 0] * nrm);
    atomicAdd(&acc2[d * 3 + 1], t2[s * 3 + 1] * nrm);
    atomicAdd(&acc2[d * 3 + 2], t2[s * 3 + 2] * nrm);
}

// ---------------- K7: + bias, log_softmax ------------------------------------
__global__ void fink(const float* __restrict__ acc2, const float* __restrict__ b2g,
                     float* __restrict__ out)
{
    const int n = blockIdx.x * 256 + threadIdx.x;
    if (n >= N_NODES) return;
    const float z0 = acc2[n * 3 + 0] + b2g[0];
    const float z1 = acc2[n * 3 + 1] + b2g[1];
    const float z2 = acc2[n * 3 + 2] + b2g[2];
    const float m = fmaxf(z0, fmaxf(z1, z2));
    const float l = m + logf(expf(z0 - m) + expf(z1 - m) + expf(z2 - m));
    out[n * 3 + 0] = z0 - l;
    out[n * 3 + 1] = z1 - l;
    out[n * 3 + 2] = z2 - l;
}

extern "C" void kernel_launch(void* const* d_in, const int* in_sizes, int n_in,
                              void* d_out, int out_size, void* d_ws, size_t ws_size,
                              hipStream_t stream)
{
    const float* x   = (const float*)d_in[0];
    const float* w1  = (const float*)d_in[1];
    const float* b1  = (const float*)d_in[2];
    const float* w2  = (const float*)d_in[3];
    const float* b2  = (const float*)d_in[4];
    const float* g1w = (const float*)d_in[5];
    const float* g1b = (const float*)d_in[6];
    const float* g2w = (const float*)d_in[7];
    const float* g2b = (const float*)d_in[8];
    const int*   ei  = (const int*)d_in[9];
    const int* src = ei;
    const int* dst = ei + NEDGE;

    float* ws   = (float*)d_ws;
    float* h0   = ws;               // 480000
    float* deg  = ws + 480000;      // 30000
    float* dinv = ws + 510000;      // 30000
    float* t1   = ws + 540000;      // 480000
    float* acc1 = ws + 1020000;     // 480000
    float* t2   = ws + 1500000;     // 90000
    float* acc2 = ws + 1590000;     // 90000
    float* out  = (float*)d_out;

    conv_fused<<<N_NODES, 256, 0, stream>>>(x, w1, b1, w2, b2, h0, deg);
    deg_kernel<<<(NEDGE + 255) / 256, 256, 0, stream>>>(dst, deg);
    gcn1_pre<<<(N_NODES * HID) / 256, 256, 0, stream>>>(h0, g1w, deg, dinv, t1, acc1);
    scat1<<<(NEDGE * 16) / 256, 256, 0, stream>>>(src, dst, dinv, t1, acc1);
    gcn_mid<<<(N_NODES + 255) / 256, 256, 0, stream>>>(acc1, g1b, g2w, dinv, t2, acc2);
    scat2<<<(NEDGE + 255) / 256, 256, 0, stream>>>(src, dst, dinv, t2, acc2);
    fink<<<(N_NODES + 255) / 256, 256, 0, stream>>>(acc2, g2b, out);
}

// Round 2
// 538.860 us; speedup vs baseline: 1.3740x; 1.3740x over previous
//
#include <hip/hip_runtime.h>

#define N_NODES 30000
#define F_INLEN 500
#define HID 16
#define OUTC 3
#define NEDGE 960000

typedef float f32x4 __attribute__((ext_vector_type(4)));
typedef short s16x8 __attribute__((ext_vector_type(8)));

static __device__ __forceinline__ unsigned short f2bf(float f) {
    unsigned int u = __float_as_uint(f);
    unsigned int r = (u + 0x7fffu + ((u >> 16) & 1u)) >> 16;
    return (unsigned short)r;
}
static __device__ __forceinline__ float bf2f(unsigned short h) {
    return __uint_as_float(((unsigned int)h) << 16);
}

// ---------------- K1: conv1 -> relu -> conv2(MFMA bf16 hi/lo split) -> relu -> max
// One block per node, 256 threads = 4 waves.
// ypad stored position-major [516 rows][16 ch] bf16 (row r = y1 at position r-1;
// rows 0 and 501..515 zero). im2col row p = 48 contiguous elements at ypad[p*16].
__global__ __launch_bounds__(256, 4) void conv_fused(
    const float* __restrict__ x,
    const float* __restrict__ w1, const float* __restrict__ b1,
    const float* __restrict__ w2, const float* __restrict__ b2,
    float* __restrict__ h0, float* __restrict__ deg)
{
    __shared__ __align__(16) float xp[502];
    __shared__ __align__(16) unsigned short yh[516 * 16];
    __shared__ __align__(16) unsigned short yl[516 * 16];
    __shared__ __align__(16) float wsm[768];
    __shared__ float red[64];

    const int tid  = threadIdx.x;
    const int node = blockIdx.x;
    const int lane = tid & 63;
    const int wave = tid >> 6;
    const int n16  = lane & 15;       // MFMA col (output channel) / A row within tile
    const int q    = lane >> 4;       // quad 0..3

    // ---- phase 0: stage x, w2; zero pad rows; seed deg ----
    for (int t = tid; t < 768; t += 256) wsm[t] = w2[t];
    if (tid == 0) { deg[node] = 1.0f; xp[0] = 0.f; xp[501] = 0.f; }
    if (tid < 125) {
        const float4 v = ((const float4*)(x + (long long)node * F_INLEN))[tid];
        xp[4 * tid + 1] = v.x; xp[4 * tid + 2] = v.y;
        xp[4 * tid + 3] = v.z; xp[4 * tid + 4] = v.w;
    }
    {   // zero rows 0 and 501..515 (16 rows x 16 ch); one entry per thread
        const int ri = tid >> 4;
        const int row = (ri == 0) ? 0 : (500 + ri);
        yh[row * 16 + (tid & 15)] = 0;
        yl[row * 16 + (tid & 15)] = 0;
    }
    __syncthreads();

    // ---- phase 1: conv1 + relu, write position-major bf16 hi/lo ----
    for (int p = tid; p < 500; p += 256) {
        const float x0 = xp[p], x1 = xp[p + 1], x2 = xp[p + 2];
        unsigned int hpack[8], lpack[8];
#pragma unroll
        for (int ci = 0; ci < 16; ci++) {
            const float v = fmaxf(b1[ci] + w1[ci * 3 + 0] * x0 + w1[ci * 3 + 1] * x1
                                         + w1[ci * 3 + 2] * x2, 0.f);
            const unsigned short h = f2bf(v);
            const unsigned short l = f2bf(v - bf2f(h));
            if (ci & 1) { hpack[ci >> 1] |= ((unsigned)h) << 16; lpack[ci >> 1] |= ((unsigned)l) << 16; }
            else        { hpack[ci >> 1] = h;                    lpack[ci >> 1] = l; }
        }
        uint4* dh = (uint4*)&yh[(p + 1) * 16];
        dh[0] = make_uint4(hpack[0], hpack[1], hpack[2], hpack[3]);
        dh[1] = make_uint4(hpack[4], hpack[5], hpack[6], hpack[7]);
        uint4* dl = (uint4*)&yl[(p + 1) * 16];
        dl[0] = make_uint4(lpack[0], lpack[1], lpack[2], lpack[3]);
        dl[1] = make_uint4(lpack[4], lpack[5], lpack[6], lpack[7]);
    }

    // B fragments (built from LDS w2 copy; valid after phase-0 barrier).
    // B[c][o]: c = t*16 + i (c<48), o = n16. Frag: lane holds B[s*32 + q*8 + j][n16].
    s16x8 bh0, bh1, bl0, bl1;
#pragma unroll
    for (int j = 0; j < 8; j++) {
        {   // s = 0
            const int c = q * 8 + j;
            const int t = c >> 4, i = c & 15;
            const float v = wsm[n16 * 48 + i * 3 + t];
            const unsigned short h = f2bf(v);
            bh0[j] = (short)h;
            bl0[j] = (short)f2bf(v - bf2f(h));
        }
        {   // s = 1
            const int c = 32 + q * 8 + j;
            float v = 0.f;
            if (c < 48) { const int t = c >> 4, i = c & 15; v = wsm[n16 * 48 + i * 3 + t]; }
            const unsigned short h = f2bf(v);
            bh1[j] = (short)h;
            bl1[j] = (short)f2bf(v - bf2f(h));
        }
    }
    __syncthreads();

    // ---- phase 2: MFMA over 32 M-tiles (8 per wave), hi/lo split, fused max ----
    float mx0 = -3.0e38f, mx1 = -3.0e38f, mx2 = -3.0e38f, mx3 = -3.0e38f;
#pragma unroll
    for (int it = 0; it < 8; it++) {
        const int tile = wave * 8 + it;
        const int abase = (tile * 16 + n16) * 16;   // A row start (elements)
        const s16x8 ah0 = *(const s16x8*)&yh[abase + q * 8];
        const s16x8 al0 = *(const s16x8*)&yl[abase + q * 8];
        const s16x8 ah1 = *(const s16x8*)&yh[abase + 32 + q * 8];
        const s16x8 al1 = *(const s16x8*)&yl[abase + 32 + q * 8];
        f32x4 acc = {0.f, 0.f, 0.f, 0.f};
        acc = __builtin_amdgcn_mfma_f32_16x16x32_bf16(ah0, bh0, acc, 0, 0, 0);
        acc = __builtin_amdgcn_mfma_f32_16x16x32_bf16(ah1, bh1, acc, 0, 0, 0);
        acc = __builtin_amdgcn_mfma_f32_16x16x32_bf16(ah0, bl0, acc, 0, 0, 0);
        acc = __builtin_amdgcn_mfma_f32_16x16x32_bf16(ah1, bl1, acc, 0, 0, 0);
        acc = __builtin_amdgcn_mfma_f32_16x16x32_bf16(al0, bh0, acc, 0, 0, 0);
        acc = __builtin_amdgcn_mfma_f32_16x16x32_bf16(al1, bh1, acc, 0, 0, 0);
        const int rb = tile * 16 + q * 4;   // C row = rb + reg; mask rows >= 500
        if (rb + 0 < 500) mx0 = fmaxf(mx0, acc[0]);
        if (rb + 1 < 500) mx1 = fmaxf(mx1, acc[1]);
        if (rb + 2 < 500) mx2 = fmaxf(mx2, acc[2]);
        if (rb + 3 < 500) mx3 = fmaxf(mx3, acc[3]);
    }
    float m = fmaxf(fmaxf(mx0, mx1), fmaxf(mx2, mx3));
    m = fmaxf(m, __shfl_xor(m, 16));
    m = fmaxf(m, __shfl_xor(m, 32));
    if (lane < 16) red[wave * 16 + lane] = m;
    __syncthreads();
    if (tid < 16) {
        const float mm = fmaxf(fmaxf(red[tid], red[16 + tid]), fmaxf(red[32 + tid], red[48 + tid]));
        h0[node * HID + tid] = fmaxf(mm + b2[tid], 0.f);
    }
}

// ---------------- K2: in-degree (+1 self-loop seeded in K1) ------------------
__global__ void deg_kernel(const int* __restrict__ dst, float* __restrict__ deg)
{
    int e = blockIdx.x * 256 + threadIdx.x;
    if (e < NEDGE) atomicAdd(&deg[dst[e]], 1.0f);
}

// ---------------- K3: t1 = h0 @ W1; acc1 = self-loop term; dinv --------------
__global__ void gcn1_pre(const float* __restrict__ h0, const float* __restrict__ W1,
                         const float* __restrict__ deg, float* __restrict__ dinv,
                         float* __restrict__ t1, float* __restrict__ acc1)
{
    __shared__ float wsm[256];
    const int tid = threadIdx.x;
    wsm[tid] = W1[tid];
    __syncthreads();
    const int gid = blockIdx.x * 256 + tid;
    const int n = gid >> 4, o = gid & 15;
    if (n >= N_NODES) return;
    const float di = rsqrtf(deg[n]);
    if (o == 0) dinv[n] = di;
    float hrow[16];
    const float4* hr = (const float4*)(h0 + n * HID);
#pragma unroll
    for (int q = 0; q < 4; q++) *(float4*)&hrow[4 * q] = hr[q];
    float t = 0.f;
#pragma unroll
    for (int i = 0; i < 16; i++) t = fmaf(hrow[i], wsm[i * 16 + o], t);
    t1[gid] = t;
    acc1[gid] = t * di * di;
}

// ---------------- K4: edge scatter layer 1 (16 lanes per edge) ---------------
__global__ void scat1(const int* __restrict__ src, const int* __restrict__ dst,
                      const float* __restrict__ dinv, const float* __restrict__ t1,
                      float* __restrict__ acc1)
{
    const int idx = blockIdx.x * 256 + threadIdx.x;
    if (idx >= NEDGE * 16) return;
    const int e = idx >> 4, o = idx & 15;
    const int s = src[e], d = dst[e];
    const float nrm = dinv[s] * dinv[d];
    atomicAdd(&acc1[d * HID + o], t1[s * HID + o] * nrm);
}

// ---------------- K5: h1 = relu(acc1+b); t2 = h1 @ W2; acc2 self term --------
__global__ void gcn_mid(const float* __restrict__ acc1, const float* __restrict__ b1g,
                        const float* __restrict__ W2, const float* __restrict__ dinv,
                        float* __restrict__ t2, float* __restrict__ acc2)
{
    __shared__ float wsm[48];
    __shared__ float bsm[16];
    const int tid = threadIdx.x;
    if (tid < 48) wsm[tid] = W2[tid];
    if (tid < 16) bsm[tid] = b1g[tid];
    __syncthreads();
    const int n = blockIdx.x * 256 + tid;
    if (n >= N_NODES) return;
    float h[16];
    const float4* ar = (const float4*)(acc1 + n * HID);
#pragma unroll
    for (int q = 0; q < 4; q++) {
        float4 v = ar[q];
        h[4 * q + 0] = fmaxf(v.x + bsm[4 * q + 0], 0.f);
        h[4 * q + 1] = fmaxf(v.y + bsm[4 * q + 1], 0.f);
        h[4 * q + 2] = fmaxf(v.z + bsm[4 * q + 2], 0.f);
        h[4 * q + 3] = fmaxf(v.w + bsm[4 * q + 3], 0.f);
    }
    const float di = dinv[n];
    const float d2 = di * di;
#pragma unroll
    for (int j = 0; j < 3; j++) {
        float t = 0.f;
#pragma unroll
        for (int i = 0; i < 16; i++) t = fmaf(h[i], wsm[i * 3 + j], t);
        t2[n * 3 + j] = t;
        acc2[n * 3 + j] = t * d2;
    }
}

// ---------------- K6: edge scatter layer 2 -----------------------------------
__global__ void scat2(const int* __restrict__ src, const int* __restrict__ dst,
                      const float* __restrict__ dinv, const float* __restrict__ t2,
                      float* __restrict__ acc2)
{
    const int e = blockIdx.x * 256 + threadIdx.x;
    if (e >= NEDGE) return;
    const int s = src[e], d = dst[e];
    const float nrm = dinv[s] * dinv[d];
    atomicAdd(&acc2[d * 3 + 0], t2[s * 3 + 0] * nrm);
    atomicAdd(&acc2[d * 3 + 1], t2[s * 3 + 1] * nrm);
    atomicAdd(&acc2[d * 3 + 2], t2[s * 3 + 2] * nrm);
}

// ---------------- K7: + bias, log_softmax ------------------------------------
__global__ void fink(const float* __restrict__ acc2, const float* __restrict__ b2g,
                     float* __restrict__ out)
{
    const int n = blockIdx.x * 256 + threadIdx.x;
    if (n >= N_NODES) return;
    const float z0 = acc2[n * 3 + 0] + b2g[0];
    const float z1 = acc2[n * 3 + 1] + b2g[1];
    const float z2 = acc2[n * 3 + 2] + b2g[2];
    const float m = fmaxf(z0, fmaxf(z1, z2));
    const float l = m + logf(expf(z0 - m) + expf(z1 - m) + expf(z2 - m));
    out[n * 3 + 0] = z0 - l;
    out[n * 3 + 1] = z1 - l;
    out[n * 3 + 2] = z2 - l;
}

extern "C" void kernel_launch(void* const* d_in, const int* in_sizes, int n_in,
                              void* d_out, int out_size, void* d_ws, size_t ws_size,
                              hipStream_t stream)
{
    const float* x   = (const float*)d_in[0];
    const float* w1  = (const float*)d_in[1];
    const float* b1  = (const float*)d_in[2];
    const float* w2  = (const float*)d_in[3];
    const float* b2  = (const float*)d_in[4];
    const float* g1w = (const float*)d_in[5];
    const float* g1b = (const float*)d_in[6];
    const float* g2w = (const float*)d_in[7];
    const float* g2b = (const float*)d_in[8];
    const int*   ei  = (const int*)d_in[9];
    const int* src = ei;
    const int* dst = ei + NEDGE;

    float* ws   = (float*)d_ws;
    float* h0   = ws;               // 480000
    float* deg  = ws + 480000;      // 30000
    float* dinv = ws + 510000;      // 30000
    float* t1   = ws + 540000;      // 480000
    float* acc1 = ws + 1020000;     // 480000
    float* t2   = ws + 1500000;     // 90000
    float* acc2 = ws + 1590000;     // 90000
    float* out  = (float*)d_out;

    conv_fused<<<N_NODES, 256, 0, stream>>>(x, w1, b1, w2, b2, h0, deg);
    deg_kernel<<<(NEDGE + 255) / 256, 256, 0, stream>>>(dst, deg);
    gcn1_pre<<<(N_NODES * HID) / 256, 256, 0, stream>>>(h0, g1w, deg, dinv, t1, acc1);
    scat1<<<(NEDGE * 16) / 256, 256, 0, stream>>>(src, dst, dinv, t1, acc1);
    gcn_mid<<<(N_NODES + 255) / 256, 256, 0, stream>>>(acc1, g1b, g2w, dinv, t2, acc2);
    scat2<<<(NEDGE + 255) / 256, 256, 0, stream>>>(src, dst, dinv, t2, acc2);
    fink<<<(N_NODES + 255) / 256, 256, 0, stream>>>(acc2, g2b, out);
}

// Round 3
// 440.305 us; speedup vs baseline: 1.6816x; 1.2238x over previous
//
#include <hip/hip_runtime.h>
#include <hip/hip_bf16.h>

#define N_NODES 30000
#define F_INLEN 500
#define HID 16
#define OUTC 3
#define NEDGE 960000

typedef float f32x4 __attribute__((ext_vector_type(4)));
typedef short s16x8 __attribute__((ext_vector_type(8)));

static __device__ __forceinline__ unsigned short f2bf(float f) {
    unsigned int u = __float_as_uint(f);
    unsigned int r = (u + 0x7fffu + ((u >> 16) & 1u)) >> 16;
    return (unsigned short)r;
}
static __device__ __forceinline__ float bf2f(unsigned short h) {
    return __uint_as_float(((unsigned int)h) << 16);
}
static __device__ __forceinline__ unsigned int pack_bf16x2(float v0, float v1) {
#if __has_builtin(__builtin_amdgcn_cvt_pk_bf16_f32)
    typedef __bf16 bf16x2_t __attribute__((ext_vector_type(2)));
    union { bf16x2_t v; unsigned int u; } cv;
    cv.v = __builtin_amdgcn_cvt_pk_bf16_f32(v0, v1);
    return cv.u;
#else
    return (unsigned int)f2bf(v0) | (((unsigned int)f2bf(v1)) << 16);
#endif
}

// ---------------- K1: conv1 -> relu -> conv2(MFMA, A=bf16, B=bf16 hi/lo) -> relu -> max
// One block per node, 256 threads = 4 waves.
// yh stored position-major [516 rows][16 ch] bf16 (row r = conv1 out at position r-1;
// rows 0 and 501..515 zero). im2col row for output pos p = 48 contiguous elems at yh[p*16].
__global__ __launch_bounds__(256, 7) void conv_fused(
    const float* __restrict__ x,
    const float* __restrict__ w1, const float* __restrict__ b1,
    const float* __restrict__ w2, const float* __restrict__ b2,
    float* __restrict__ h0)
{
    __shared__ __align__(16) float xp[502];
    __shared__ __align__(16) unsigned short yh[516 * 16];
    __shared__ __align__(16) float wsm[768];
    __shared__ float red[64];

    const int tid  = threadIdx.x;
    const int node = blockIdx.x;
    const int lane = tid & 63;
    const int wave = tid >> 6;
    const int n16  = lane & 15;
    const int q    = lane >> 4;

    // ---- phase 0: stage x, w2; zero pad rows ----
    for (int t = tid; t < 768; t += 256) wsm[t] = w2[t];
    if (tid == 0) { xp[0] = 0.f; xp[501] = 0.f; }
    if (tid < 125) {
        const float4 v = ((const float4*)(x + (long long)node * F_INLEN))[tid];
        xp[4 * tid + 1] = v.x; xp[4 * tid + 2] = v.y;
        xp[4 * tid + 3] = v.z; xp[4 * tid + 4] = v.w;
    }
    {   // zero rows 0 and 501..515
        const int ri = tid >> 4;
        const int row = (ri == 0) ? 0 : (500 + ri);
        yh[row * 16 + (tid & 15)] = 0;
    }
    __syncthreads();

    // ---- phase 1: conv1 + relu -> bf16, position-major ----
    for (int p = tid; p < 500; p += 256) {
        const float x0 = xp[p], x1 = xp[p + 1], x2 = xp[p + 2];
        unsigned int hp[8];
#pragma unroll
        for (int cp = 0; cp < 8; cp++) {
            const int c0 = 2 * cp, c1 = 2 * cp + 1;
            const float v0 = fmaxf(b1[c0] + w1[c0 * 3] * x0 + w1[c0 * 3 + 1] * x1
                                          + w1[c0 * 3 + 2] * x2, 0.f);
            const float v1 = fmaxf(b1[c1] + w1[c1 * 3] * x0 + w1[c1 * 3 + 1] * x1
                                          + w1[c1 * 3 + 2] * x2, 0.f);
            hp[cp] = pack_bf16x2(v0, v1);
        }
        uint4* dh = (uint4*)&yh[(p + 1) * 16];
        dh[0] = make_uint4(hp[0], hp[1], hp[2], hp[3]);
        dh[1] = make_uint4(hp[4], hp[5], hp[6], hp[7]);
    }

    // B fragments from LDS w2 copy. B[c][o]: c = t*16 + i (c<48), o = n16.
    // Lane holds B[s*32 + q*8 + j][n16]. hi/lo split keeps B exact in fp32.
    s16x8 bh0, bh1, bl0, bl1;
#pragma unroll
    for (int j = 0; j < 8; j++) {
        {   // s = 0
            const int c = q * 8 + j;
            const int t = c >> 4, i = c & 15;
            const float v = wsm[n16 * 48 + i * 3 + t];
            const unsigned short h = f2bf(v);
            bh0[j] = (short)h;
            bl0[j] = (short)f2bf(v - bf2f(h));
        }
        {   // s = 1
            const int c = 32 + q * 8 + j;
            float v = 0.f;
            if (c < 48) { const int t = c >> 4, i = c & 15; v = wsm[n16 * 48 + i * 3 + t]; }
            const unsigned short h = f2bf(v);
            bh1[j] = (short)h;
            bl1[j] = (short)f2bf(v - bf2f(h));
        }
    }
    __syncthreads();

    // ---- phase 2: MFMA over 32 M-tiles (8 per wave), fused max ----
    float mx0 = -3.0e38f, mx1 = -3.0e38f, mx2 = -3.0e38f, mx3 = -3.0e38f;
#pragma unroll
    for (int it = 0; it < 8; it++) {
        const int tile = wave * 8 + it;
        const int abase = (tile * 16 + n16) * 16;
        const s16x8 ah0 = *(const s16x8*)&yh[abase + q * 8];
        const s16x8 ah1 = *(const s16x8*)&yh[abase + 32 + q * 8];
        f32x4 acc = {0.f, 0.f, 0.f, 0.f};
        acc = __builtin_amdgcn_mfma_f32_16x16x32_bf16(ah0, bh0, acc, 0, 0, 0);
        acc = __builtin_amdgcn_mfma_f32_16x16x32_bf16(ah1, bh1, acc, 0, 0, 0);
        acc = __builtin_amdgcn_mfma_f32_16x16x32_bf16(ah0, bl0, acc, 0, 0, 0);
        acc = __builtin_amdgcn_mfma_f32_16x16x32_bf16(ah1, bl1, acc, 0, 0, 0);
        const int rb = tile * 16 + q * 4;
        if (rb + 0 < 500) mx0 = fmaxf(mx0, acc[0]);
        if (rb + 1 < 500) mx1 = fmaxf(mx1, acc[1]);
        if (rb + 2 < 500) mx2 = fmaxf(mx2, acc[2]);
        if (rb + 3 < 500) mx3 = fmaxf(mx3, acc[3]);
    }
    float m = fmaxf(fmaxf(mx0, mx1), fmaxf(mx2, mx3));
    m = fmaxf(m, __shfl_xor(m, 16));
    m = fmaxf(m, __shfl_xor(m, 32));
    if (lane < 16) red[wave * 16 + lane] = m;
    __syncthreads();
    if (tid < 16) {
        const float mm = fmaxf(fmaxf(red[tid], red[16 + tid]), fmaxf(red[32 + tid], red[48 + tid]));
        h0[node * HID + tid] = fmaxf(mm + b2[tid], 0.f);
    }
}

// ---------------- K2: in-degree count (int) ----------------------------------
__global__ void deg_count(const int* __restrict__ dst, int* __restrict__ degi)
{
    const int e = blockIdx.x * 256 + threadIdx.x;
    if (e < NEDGE) atomicAdd(&degi[dst[e]], 1);
}

// ---------------- K3: single-block scan -> rowptr, fill, dinv ----------------
__global__ void scan_kernel(const int* __restrict__ degi, int* __restrict__ rowptr,
                            int* __restrict__ fill, float* __restrict__ dinv)
{
    __shared__ int part[256];
    __shared__ int base[256];
    const int tid = threadIdx.x;
    const int lo = tid * 118;
    const int hi = (lo + 118 < N_NODES) ? lo + 118 : N_NODES;
    int s = 0;
    for (int i = lo; i < hi; ++i) s += degi[i];
    part[tid] = s;
    __syncthreads();
    if (tid == 0) {
        int run = 0;
        for (int t = 0; t < 256; ++t) { base[t] = run; run += part[t]; }
        rowptr[N_NODES] = run;    // == NEDGE
    }
    __syncthreads();
    int run = base[tid];
    for (int i = lo; i < hi; ++i) {
        rowptr[i] = run;
        fill[i]   = run;
        const int d = degi[i];
        dinv[i] = rsqrtf((float)(d + 1));   // +1 self-loop
        run += d;
    }
}

// ---------------- K4: bucket src ids by dst (CSR build) ----------------------
__global__ void bucket_kernel(const int* __restrict__ src, const int* __restrict__ dst,
                              int* __restrict__ fill, int* __restrict__ srcb)
{
    const int e = blockIdx.x * 256 + threadIdx.x;
    if (e < NEDGE) {
        const int d = dst[e];
        const int pos = atomicAdd(&fill[d], 1);
        srcb[pos] = src[e];
    }
}

// ---------------- K5: t1p = dinv[n] * (h0[n] @ W1) ---------------------------
__global__ void gcn1_pre(const float* __restrict__ h0, const float* __restrict__ W1,
                         const float* __restrict__ dinv, float* __restrict__ t1p)
{
    __shared__ float wsm[256];
    const int tid = threadIdx.x;
    wsm[tid] = W1[tid];
    __syncthreads();
    const int gid = blockIdx.x * 256 + tid;
    const int n = gid >> 4, o = gid & 15;
    float hrow[16];
    const float4* hr = (const float4*)(h0 + n * HID);
#pragma unroll
    for (int q = 0; q < 4; q++) *(float4*)&hrow[4 * q] = hr[q];
    float t = 0.f;
#pragma unroll
    for (int i = 0; i < 16; i++) t = fmaf(hrow[i], wsm[i * 16 + o], t);
    t1p[gid] = t * dinv[n];
}

// ---------------- K6: gather layer1 + relu + (16->3 GEMM) fused --------------
// 16 lanes per node; t2p[n] = dinv[n] * (relu(b1 + dinv[n]*S[n]) @ W2)
__global__ __launch_bounds__(256) void gather1(
    const int* __restrict__ rowptr, const int* __restrict__ srcb,
    const float* __restrict__ t1p, const float* __restrict__ dinv,
    const float* __restrict__ b1g, const float* __restrict__ W2,
    float* __restrict__ t2p)
{
    const int tid  = threadIdx.x;
    const int node = blockIdx.x * 16 + (tid >> 4);
    const int o    = tid & 15;
    const int beg = rowptr[node], end = rowptr[node + 1];
    float acc = t1p[node * HID + o];          // self-loop term
    int i = beg;
    int sNext = (i < end) ? srcb[i] : 0;
    while (i < end) {
        const int sCur = sNext;
        ++i;
        if (i < end) sNext = srcb[i];
        acc += t1p[sCur * HID + o];
    }
    const float dv = dinv[node];
    const float h = fmaxf(b1g[o] + dv * acc, 0.f);
    float d0 = h * W2[o * 3 + 0];
    float d1 = h * W2[o * 3 + 1];
    float d2 = h * W2[o * 3 + 2];
#pragma unroll
    for (int msk = 1; msk < 16; msk <<= 1) {
        d0 += __shfl_xor(d0, msk);
        d1 += __shfl_xor(d1, msk);
        d2 += __shfl_xor(d2, msk);
    }
    if (o == 0) t2p[node * 3 + 0] = d0 * dv;
    if (o == 1) t2p[node * 3 + 1] = d1 * dv;
    if (o == 2) t2p[node * 3 + 2] = d2 * dv;
}

// ---------------- K7: gather layer2 + bias + log_softmax ---------------------
// 4 lanes per node (3 active channels)
__global__ __launch_bounds__(256) void gather2(
    const int* __restrict__ rowptr, const int* __restrict__ srcb,
    const float* __restrict__ t2p, const float* __restrict__ dinv,
    const float* __restrict__ b2g, float* __restrict__ out)
{
    const int tid  = threadIdx.x;
    const int node = blockIdx.x * 64 + (tid >> 2);
    if (node >= N_NODES) return;
    const int j = tid & 3;
    const int beg = rowptr[node], end = rowptr[node + 1];
    float acc = (j < 3) ? t2p[node * 3 + j] : 0.f;   // self-loop
    int i = beg;
    int sNext = (i < end) ? srcb[i] : 0;
    while (i < end) {
        const int sCur = sNext;
        ++i;
        if (i < end) sNext = srcb[i];
        if (j < 3) acc += t2p[sCur * 3 + j];
    }
    const float z = (j < 3) ? (b2g[j] + dinv[node] * acc) : -1.0e30f;
    const int wl = tid & 63;
    const int gb = wl & ~3;
    const float z0 = __shfl(z, gb + 0);
    const float z1 = __shfl(z, gb + 1);
    const float z2 = __shfl(z, gb + 2);
    const float m = fmaxf(z0, fmaxf(z1, z2));
    const float l = m + logf(expf(z0 - m) + expf(z1 - m) + expf(z2 - m));
    if (j < 3) out[node * 3 + j] = z - l;
}

extern "C" void kernel_launch(void* const* d_in, const int* in_sizes, int n_in,
                              void* d_out, int out_size, void* d_ws, size_t ws_size,
                              hipStream_t stream)
{
    const float* x   = (const float*)d_in[0];
    const float* w1  = (const float*)d_in[1];
    const float* b1  = (const float*)d_in[2];
    const float* w2  = (const float*)d_in[3];
    const float* b2  = (const float*)d_in[4];
    const float* g1w = (const float*)d_in[5];
    const float* g1b = (const float*)d_in[6];
    const float* g2w = (const float*)d_in[7];
    const float* g2b = (const float*)d_in[8];
    const int*   ei  = (const int*)d_in[9];
    const int* src = ei;
    const int* dst = ei + NEDGE;

    float* ws    = (float*)d_ws;
    float* h0    = ws;                        // 480000 f
    float* t1p   = ws + 480000;               // 480000 f
    float* t2p   = ws + 960000;               // 90000 f
    float* dinv  = ws + 1050000;              // 30000 f
    int*   rowptr= (int*)(ws + 1080000);      // 30001 i
    int*   fill  = (int*)(ws + 1110004);      // 30000 i
    int*   degi  = (int*)(ws + 1140004);      // 30000 i
    int*   srcb  = (int*)(ws + 1170004);      // 960000 i
    float* out   = (float*)d_out;

    hipMemsetAsync(degi, 0, N_NODES * sizeof(int), stream);
    conv_fused<<<N_NODES, 256, 0, stream>>>(x, w1, b1, w2, b2, h0);
    deg_count<<<(NEDGE + 255) / 256, 256, 0, stream>>>(dst, degi);
    scan_kernel<<<1, 256, 0, stream>>>(degi, rowptr, fill, dinv);
    bucket_kernel<<<(NEDGE + 255) / 256, 256, 0, stream>>>(src, dst, fill, srcb);
    gcn1_pre<<<(N_NODES * HID) / 256, 256, 0, stream>>>(h0, g1w, dinv, t1p);
    gather1<<<N_NODES / 16, 256, 0, stream>>>(rowptr, srcb, t1p, dinv, g1b, g2w, t2p);
    gather2<<<(N_NODES + 63) / 64, 256, 0, stream>>>(rowptr, srcb, t2p, dinv, g2b, out);
}

// Round 4
// 364.350 us; speedup vs baseline: 2.0321x; 1.2085x over previous
//
#include <hip/hip_runtime.h>
#include <hip/hip_bf16.h>

#define N_NODES 30000
#define F_INLEN 500
#define HID 16
#define OUTC 3
#define NEDGE 960000
#define EPB (NEDGE / N_NODES)   // 32 edges per conv block

typedef float f32x4 __attribute__((ext_vector_type(4)));
typedef short s16x8 __attribute__((ext_vector_type(8)));

static __device__ __forceinline__ unsigned short f2bf(float f) {
    unsigned int u = __float_as_uint(f);
    unsigned int r = (u + 0x7fffu + ((u >> 16) & 1u)) >> 16;
    return (unsigned short)r;
}
static __device__ __forceinline__ float bf2f(unsigned short h) {
    return __uint_as_float(((unsigned int)h) << 16);
}
static __device__ __forceinline__ unsigned int pack_bf16x2(float v0, float v1) {
#if __has_builtin(__builtin_amdgcn_cvt_pk_bf16_f32)
    typedef __bf16 bf16x2_t __attribute__((ext_vector_type(2)));
    union { bf16x2_t v; unsigned int u; } cv;
    cv.v = __builtin_amdgcn_cvt_pk_bf16_f32(v0, v1);
    return cv.u;
#else
    return (unsigned int)f2bf(v0) | (((unsigned int)f2bf(v1)) << 16);
#endif
}

// ---------------- K0: precompute conv2 B-fragments (hi/lo) once --------------
// Layout: bfragsG[lane*32 + {0..7:bh0, 8..15:bh1, 16..23:bl0, 24..31:bl1}]
__global__ void bfrag_setup(const float* __restrict__ w2, short* __restrict__ bfragsG)
{
    const int lane = threadIdx.x;      // 64 threads
    const int n16 = lane & 15, q = lane >> 4;
    short out[32];
#pragma unroll
    for (int j = 0; j < 8; j++) {
        {   // s = 0
            const int c = q * 8 + j;
            const int t = c >> 4, i = c & 15;
            const float v = w2[n16 * 48 + i * 3 + t];
            const unsigned short h = f2bf(v);
            out[j]      = (short)h;
            out[16 + j] = (short)f2bf(v - bf2f(h));
        }
        {   // s = 1
            const int c = 32 + q * 8 + j;
            float v = 0.f;
            if (c < 48) { const int t = c >> 4, i = c & 15; v = w2[n16 * 48 + i * 3 + t]; }
            const unsigned short h = f2bf(v);
            out[8 + j]  = (short)h;
            out[24 + j] = (short)f2bf(v - bf2f(h));
        }
    }
#pragma unroll
    for (int k = 0; k < 32; k++) bfragsG[lane * 32 + k] = out[k];
}

// ---------------- K1: conv1 -> relu -> conv2(MFMA) -> relu -> max  (+deg atomics)
__global__ __launch_bounds__(256, 8) void conv_fused(
    const float* __restrict__ x,
    const float* __restrict__ w1, const float* __restrict__ b1,
    const float* __restrict__ b2, const short* __restrict__ bfragsG,
    const int* __restrict__ dst, int* __restrict__ degi,
    float* __restrict__ h0)
{
    __shared__ __align__(16) float xp[502];
    __shared__ __align__(16) unsigned short yh[516 * 16];
    __shared__ float red[64];

    const int tid  = threadIdx.x;
    const int node = blockIdx.x;
    const int lane = tid & 63;
    const int wave = tid >> 6;
    const int n16  = lane & 15;
    const int q    = lane >> 4;

    // ---- overlapped edge-degree chunk (32 edges per block) ----
    if (tid < EPB) {
        const int e = node * EPB + tid;
        atomicAdd(&degi[dst[e]], 1);
    }

    // ---- phase 0: stage x; zero pad rows; load B fragments ----
    if (tid == 0) { xp[0] = 0.f; xp[501] = 0.f; }
    if (tid < 125) {
        const float4 v = ((const float4*)(x + (long long)node * F_INLEN))[tid];
        xp[4 * tid + 1] = v.x; xp[4 * tid + 2] = v.y;
        xp[4 * tid + 3] = v.z; xp[4 * tid + 4] = v.w;
    }
    {   // zero rows 0 and 501..515
        const int ri = tid >> 4;
        const int row = (ri == 0) ? 0 : (500 + ri);
        yh[row * 16 + (tid & 15)] = 0;
    }
    const s16x8* bfp = (const s16x8*)(bfragsG + lane * 32);
    const s16x8 bh0 = bfp[0], bh1 = bfp[1], bl0 = bfp[2], bl1 = bfp[3];
    __syncthreads();

    // ---- phase 1: conv1 + relu -> bf16, position-major ----
    for (int p = tid; p < 500; p += 256) {
        const float x0 = xp[p], x1 = xp[p + 1], x2 = xp[p + 2];
        unsigned int hp[8];
#pragma unroll
        for (int cp = 0; cp < 8; cp++) {
            const int c0 = 2 * cp, c1 = 2 * cp + 1;
            const float v0 = fmaxf(b1[c0] + w1[c0 * 3] * x0 + w1[c0 * 3 + 1] * x1
                                          + w1[c0 * 3 + 2] * x2, 0.f);
            const float v1 = fmaxf(b1[c1] + w1[c1 * 3] * x0 + w1[c1 * 3 + 1] * x1
                                          + w1[c1 * 3 + 2] * x2, 0.f);
            hp[cp] = pack_bf16x2(v0, v1);
        }
        uint4* dh = (uint4*)&yh[(p + 1) * 16];
        dh[0] = make_uint4(hp[0], hp[1], hp[2], hp[3]);
        dh[1] = make_uint4(hp[4], hp[5], hp[6], hp[7]);
    }
    __syncthreads();

    // ---- phase 2: MFMA over 32 M-tiles (8 per wave), fused max ----
    float mx0 = -3.0e38f, mx1 = -3.0e38f, mx2 = -3.0e38f, mx3 = -3.0e38f;
#pragma unroll
    for (int it = 0; it < 8; it++) {
        const int tile = wave * 8 + it;
        const int abase = (tile * 16 + n16) * 16;
        const s16x8 ah0 = *(const s16x8*)&yh[abase + q * 8];
        const s16x8 ah1 = *(const s16x8*)&yh[abase + 32 + q * 8];
        f32x4 acc = {0.f, 0.f, 0.f, 0.f};
        acc = __builtin_amdgcn_mfma_f32_16x16x32_bf16(ah0, bh0, acc, 0, 0, 0);
        acc = __builtin_amdgcn_mfma_f32_16x16x32_bf16(ah1, bh1, acc, 0, 0, 0);
        acc = __builtin_amdgcn_mfma_f32_16x16x32_bf16(ah0, bl0, acc, 0, 0, 0);
        acc = __builtin_amdgcn_mfma_f32_16x16x32_bf16(ah1, bl1, acc, 0, 0, 0);
        const int rb = tile * 16 + q * 4;
        if (rb + 0 < 500) mx0 = fmaxf(mx0, acc[0]);
        if (rb + 1 < 500) mx1 = fmaxf(mx1, acc[1]);
        if (rb + 2 < 500) mx2 = fmaxf(mx2, acc[2]);
        if (rb + 3 < 500) mx3 = fmaxf(mx3, acc[3]);
    }
    float m = fmaxf(fmaxf(mx0, mx1), fmaxf(mx2, mx3));
    m = fmaxf(m, __shfl_xor(m, 16));
    m = fmaxf(m, __shfl_xor(m, 32));
    if (lane < 16) red[wave * 16 + lane] = m;
    __syncthreads();
    if (tid < 16) {
        const float mm = fmaxf(fmaxf(red[tid], red[16 + tid]), fmaxf(red[32 + tid], red[48 + tid]));
        h0[node * HID + tid] = fmaxf(mm + b2[tid], 0.f);
    }
}

// ---------------- K2: parallel scan -> rowptr, fill, dinv --------------------
__global__ __launch_bounds__(1024) void scan_kernel(
    const int* __restrict__ degi, int* __restrict__ rowptr,
    int* __restrict__ fill, float* __restrict__ dinv)
{
    __shared__ int waveTot[16];
    const int tid = threadIdx.x;
    const int lane = tid & 63;
    const int wid = tid >> 6;
    const int lo = tid * 30;
    const int hi = (lo + 30 < N_NODES) ? lo + 30 : N_NODES;
    int s = 0;
    for (int i = lo; i < hi; ++i) s += degi[i];
    // inclusive scan within wave
    int xinc = s;
#pragma unroll
    for (int off = 1; off < 64; off <<= 1) {
        const int y = __shfl_up(xinc, off);
        if (lane >= off) xinc += y;
    }
    if (lane == 63) waveTot[wid] = xinc;
    __syncthreads();
    if (tid == 0) {
        int run = 0;
#pragma unroll
        for (int w = 0; w < 16; w++) { const int t = waveTot[w]; waveTot[w] = run; run += t; }
        rowptr[N_NODES] = run;   // == NEDGE
    }
    __syncthreads();
    int run = waveTot[wid] + xinc - s;   // exclusive prefix for this thread
    for (int i = lo; i < hi; ++i) {
        const int d = degi[i];
        rowptr[i] = run;
        fill[i]   = run;
        dinv[i]   = rsqrtf((float)(d + 1));
        run += d;
    }
}

// ---------------- K3: bucket CSR build + h0 prescale (fused) -----------------
__global__ void bucket_pre(const int* __restrict__ src, const int* __restrict__ dst,
                           int* __restrict__ fill, int* __restrict__ srcb,
                           const float* __restrict__ h0, const float* __restrict__ dinv,
                           float* __restrict__ h0p)
{
    const int tid = threadIdx.x;
    if (blockIdx.x < NEDGE / 256) {
        const int e = blockIdx.x * 256 + tid;
        const int d = dst[e];
        const int pos = atomicAdd(&fill[d], 1);
        srcb[pos] = src[e];
    } else {
        const int gid = (blockIdx.x - NEDGE / 256) * 256 + tid;
        h0p[gid] = h0[gid] * dinv[gid >> 4];
    }
}

// ---------------- K4: gather1: agg(h0p) -> W1+relu -> W2 -> t2p --------------
// 16 lanes per node. h1 = relu(b1 + dinv*(agg@W1)); t2p = dinv*(h1@W2)
__global__ __launch_bounds__(256) void gather1(
    const int* __restrict__ rowptr, const int* __restrict__ srcb,
    const float* __restrict__ h0p, const float* __restrict__ dinv,
    const float* __restrict__ W1, const float* __restrict__ b1g,
    const float* __restrict__ W2, float* __restrict__ t2p)
{
    __shared__ float w1s[256];
    __shared__ float w2s[48];
    __shared__ float b1s[16];
    const int tid = threadIdx.x;
    w1s[tid] = W1[tid];
    if (tid < 48) w2s[tid] = W2[tid];
    if (tid < 16) b1s[tid] = b1g[tid];
    __syncthreads();

    const int node = blockIdx.x * 16 + (tid >> 4);
    const int o    = tid & 15;
    const int beg = rowptr[node], end = rowptr[node + 1];
    float acc = h0p[node * HID + o];          // self-loop term (already dinv-scaled)
    int i = beg;
    int sNext = (i < end) ? srcb[i] : 0;
    while (i < end) {
        const int sCur = sNext;
        ++i;
        if (i < end) sNext = srcb[i];
        acc += h0p[sCur * HID + o];
    }
    // agg@W1 via in-wave shfl broadcast (16-lane group)
    const int gbase = (tid & 63) & ~15;
    float y = 0.f;
#pragma unroll
    for (int i2 = 0; i2 < 16; i2++) {
        const float a = __shfl(acc, gbase + i2);
        y = fmaf(a, w1s[i2 * 16 + o], y);
    }
    const float dv = dinv[node];
    const float h = fmaxf(b1s[o] + dv * y, 0.f);
    float d0 = h * w2s[o * 3 + 0];
    float d1 = h * w2s[o * 3 + 1];
    float d2 = h * w2s[o * 3 + 2];
#pragma unroll
    for (int msk = 1; msk < 16; msk <<= 1) {
        d0 += __shfl_xor(d0, msk);
        d1 += __shfl_xor(d1, msk);
        d2 += __shfl_xor(d2, msk);
    }
    if (o < 3) {
        const float dval = (o == 0) ? d0 : (o == 1) ? d1 : d2;
        t2p[node * 3 + o] = dval * dv;
    }
}

// ---------------- K5: gather2 + bias + log_softmax ---------------------------
__global__ __launch_bounds__(256) void gather2(
    const int* __restrict__ rowptr, const int* __restrict__ srcb,
    const float* __restrict__ t2p, const float* __restrict__ dinv,
    const float* __restrict__ b2g, float* __restrict__ out)
{
    const int tid  = threadIdx.x;
    const int node = blockIdx.x * 64 + (tid >> 2);
    if (node >= N_NODES) return;
    const int j = tid & 3;
    const int beg = rowptr[node], end = rowptr[node + 1];
    float acc = (j < 3) ? t2p[node * 3 + j] : 0.f;
    int i = beg;
    int sNext = (i < end) ? srcb[i] : 0;
    while (i < end) {
        const int sCur = sNext;
        ++i;
        if (i < end) sNext = srcb[i];
        if (j < 3) acc += t2p[sCur * 3 + j];
    }
    const float z = (j < 3) ? (b2g[j] + dinv[node] * acc) : -1.0e30f;
    const int wl = tid & 63;
    const int gb = wl & ~3;
    const float z0 = __shfl(z, gb + 0);
    const float z1 = __shfl(z, gb + 1);
    const float z2 = __shfl(z, gb + 2);
    const float m = fmaxf(z0, fmaxf(z1, z2));
    const float l = m + logf(expf(z0 - m) + expf(z1 - m) + expf(z2 - m));
    if (j < 3) out[node * 3 + j] = z - l;
}

extern "C" void kernel_launch(void* const* d_in, const int* in_sizes, int n_in,
                              void* d_out, int out_size, void* d_ws, size_t ws_size,
                              hipStream_t stream)
{
    const float* x   = (const float*)d_in[0];
    const float* w1  = (const float*)d_in[1];
    const float* b1  = (const float*)d_in[2];
    const float* w2  = (const float*)d_in[3];
    const float* b2  = (const float*)d_in[4];
    const float* g1w = (const float*)d_in[5];
    const float* g1b = (const float*)d_in[6];
    const float* g2w = (const float*)d_in[7];
    const float* g2b = (const float*)d_in[8];
    const int*   ei  = (const int*)d_in[9];
    const int* src = ei;
    const int* dst = ei + NEDGE;

    float* ws    = (float*)d_ws;
    float* h0    = ws;                        // 480000 f
    float* h0p   = ws + 480000;               // 480000 f
    float* t2p   = ws + 960000;               // 90000 f
    float* dinv  = ws + 1050000;              // 30000 f
    int*   rowptr= (int*)(ws + 1080000);      // 30001 i
    int*   fill  = (int*)(ws + 1110004);      // 30000 i
    int*   degi  = (int*)(ws + 1140004);      // 30000 i
    int*   srcb  = (int*)(ws + 1170004);      // 960000 i
    short* bfragsG = (short*)(ws + 2130004);  // 2048 s
    float* out   = (float*)d_out;

    hipMemsetAsync(degi, 0, N_NODES * sizeof(int), stream);
    bfrag_setup<<<1, 64, 0, stream>>>(w2, bfragsG);
    conv_fused<<<N_NODES, 256, 0, stream>>>(x, w1, b1, b2, bfragsG, dst, degi, h0);
    scan_kernel<<<1, 1024, 0, stream>>>(degi, rowptr, fill, dinv);
    bucket_pre<<<NEDGE / 256 + (N_NODES * HID) / 256, 256, 0, stream>>>(
        src, dst, fill, srcb, h0, dinv, h0p);
    gather1<<<N_NODES / 16, 256, 0, stream>>>(rowptr, srcb, h0p, dinv, g1w, g1b, g2w, t2p);
    gather2<<<(N_NODES + 63) / 64, 256, 0, stream>>>(rowptr, srcb, t2p, dinv, g2b, out);
}

// Round 5
// 345.711 us; speedup vs baseline: 2.1417x; 1.0539x over previous
//
#include <hip/hip_runtime.h>
#include <hip/hip_bf16.h>

#define N_NODES 30000
#define F_INLEN 500
#define HID 16
#define OUTC 3
#define NEDGE 960000
#define EPB (NEDGE / N_NODES)   // 32 edges per conv block
#define YPITCH 20               // shorts per row: 40B -> conflict-free, 8B aligned

typedef float  f32x4 __attribute__((ext_vector_type(4)));
typedef float  f32x2 __attribute__((ext_vector_type(2)));
typedef short  s16x8 __attribute__((ext_vector_type(8)));

static __device__ __forceinline__ unsigned short f2bf(float f) {
    unsigned int u = __float_as_uint(f);
    unsigned int r = (u + 0x7fffu + ((u >> 16) & 1u)) >> 16;
    return (unsigned short)r;
}
static __device__ __forceinline__ unsigned int pack_bf16x2(float v0, float v1) {
#if __has_builtin(__builtin_amdgcn_cvt_pk_bf16_f32)
    typedef __bf16 bf16x2_t __attribute__((ext_vector_type(2)));
    union { bf16x2_t v; unsigned int u; } cv;
    cv.v = __builtin_amdgcn_cvt_pk_bf16_f32(v0, v1);
    return cv.u;
#else
    return (unsigned int)f2bf(v0) | (((unsigned int)f2bf(v1)) << 16);
#endif
}

// ---------------- K0: B-fragments (hi only) + zero degi ----------------------
// bfragsG[lane*16 + {0..7: bh0, 8..15: bh1}]
__global__ void setup_kernel(const float* __restrict__ w2, short* __restrict__ bfragsG,
                             int* __restrict__ degi)
{
    const int tid = threadIdx.x;
    const int gid = blockIdx.x * 256 + tid;
    if (gid < N_NODES) degi[gid] = 0;
    if (blockIdx.x == 0 && tid < 64) {
        const int n16 = tid & 15, q = tid >> 4;
#pragma unroll
        for (int j = 0; j < 8; j++) {
            {   // s = 0: c = q*8+j  (< 32, always valid)
                const int c = q * 8 + j;
                const int t = c >> 4, i = c & 15;
                bfragsG[tid * 16 + j] = (short)f2bf(w2[n16 * 48 + i * 3 + t]);
            }
            {   // s = 1: c = 32+q*8+j, zero for c >= 48
                const int c = 32 + q * 8 + j;
                short v = 0;
                if (c < 48) { const int t = c >> 4, i = c & 15; v = (short)f2bf(w2[n16 * 48 + i * 3 + t]); }
                bfragsG[tid * 16 + 8 + j] = v;
            }
        }
    }
}

// ---------------- K1: conv1 -> relu -> conv2(MFMA) -> relu -> max  (+deg atomics)
// yh position-major [516 rows][YPITCH shorts], row r = conv1 out at position r-1.
__global__ __launch_bounds__(256, 7) void conv_fused(
    const float* __restrict__ x,
    const float* __restrict__ w1, const float* __restrict__ b1,
    const float* __restrict__ b2, const short* __restrict__ bfragsG,
    const int* __restrict__ dst, int* __restrict__ degi,
    float* __restrict__ h0)
{
    __shared__ __align__(16) float xp[502];
    __shared__ __align__(16) unsigned short yh[516 * YPITCH];
    __shared__ float red[64];

    const int tid  = threadIdx.x;
    const int node = blockIdx.x;
    const int lane = tid & 63;
    const int wave = tid >> 6;
    const int n16  = lane & 15;
    const int q    = lane >> 4;

    // overlapped edge-degree chunk
    if (tid < EPB) {
        const int e = node * EPB + tid;
        atomicAdd(&degi[dst[e]], 1);
    }

    // phase 0: stage x; zero pad rows; load B fragments
    if (tid == 0) { xp[0] = 0.f; xp[501] = 0.f; }
    if (tid < 125) {
        const float4 v = ((const float4*)(x + (long long)node * F_INLEN))[tid];
        xp[4 * tid + 1] = v.x; xp[4 * tid + 2] = v.y;
        xp[4 * tid + 3] = v.z; xp[4 * tid + 4] = v.w;
    }
    {   // zero rows 0 and 501..515 (cols 0..15 only are ever read)
        const int ri = tid >> 4;
        const int row = (ri == 0) ? 0 : (500 + ri);
        yh[row * YPITCH + (tid & 15)] = 0;
    }
    const s16x8* bfp = (const s16x8*)(bfragsG + lane * 16);
    const s16x8 bh0 = bfp[0], bh1 = bfp[1];

    // conv1 weights as packed pairs (uniform -> scalar regs)
    f32x2 wt0[8], wt1[8], wt2[8], bb[8];
#pragma unroll
    for (int cp = 0; cp < 8; cp++) {
        const int c0 = 2 * cp, c1 = 2 * cp + 1;
        wt0[cp] = (f32x2){w1[c0 * 3 + 0], w1[c1 * 3 + 0]};
        wt1[cp] = (f32x2){w1[c0 * 3 + 1], w1[c1 * 3 + 1]};
        wt2[cp] = (f32x2){w1[c0 * 3 + 2], w1[c1 * 3 + 2]};
        bb[cp]  = (f32x2){b1[c0], b1[c1]};
    }
    __syncthreads();

    // phase 1: conv1 + relu -> bf16, position-major (packed f32 math)
    for (int p = tid; p < 500; p += 256) {
        const float x0 = xp[p], x1 = xp[p + 1], x2 = xp[p + 2];
        const f32x2 xv0 = {x0, x0}, xv1 = {x1, x1}, xv2 = {x2, x2};
        const f32x2 zero = {0.f, 0.f};
        unsigned int hp[8];
#pragma unroll
        for (int cp = 0; cp < 8; cp++) {
            f32x2 a = bb[cp];
            a = __builtin_elementwise_fma(wt0[cp], xv0, a);
            a = __builtin_elementwise_fma(wt1[cp], xv1, a);
            a = __builtin_elementwise_fma(wt2[cp], xv2, a);
            a = __builtin_elementwise_max(a, zero);
            hp[cp] = pack_bf16x2(a[0], a[1]);
        }
        uint2* d = (uint2*)&yh[(p + 1) * YPITCH];
        d[0] = make_uint2(hp[0], hp[1]);
        d[1] = make_uint2(hp[2], hp[3]);
        d[2] = make_uint2(hp[4], hp[5]);
        d[3] = make_uint2(hp[6], hp[7]);
    }
    __syncthreads();

    // phase 2: MFMA over 32 M-tiles (8 per wave), fused max
    struct S8 { short4 lo, hi; };
    float mx0 = -3.0e38f, mx1 = -3.0e38f, mx2 = -3.0e38f, mx3 = -3.0e38f;
#pragma unroll
    for (int it = 0; it < 8; it++) {
        const int tile = wave * 8 + it;
        const int p0 = tile * 16 + n16;          // im2col row
        const int cA = (q & 1) * 8;              // col offset (shorts)
        const int rA = p0 + (q >> 1);            // row for k in [0,32)
        const int rB = p0 + 2 + (q >> 1);        // row for k in [32,64) (junk x Bzero for q>=2)
        S8 t0, t1;
        t0.lo = *(const short4*)&yh[rA * YPITCH + cA];
        t0.hi = *(const short4*)&yh[rA * YPITCH + cA + 4];
        t1.lo = *(const short4*)&yh[rB * YPITCH + cA];
        t1.hi = *(const short4*)&yh[rB * YPITCH + cA + 4];
        const s16x8 ah0 = *(const s16x8*)&t0;
        const s16x8 ah1 = *(const s16x8*)&t1;
        f32x4 acc = {0.f, 0.f, 0.f, 0.f};
        acc = __builtin_amdgcn_mfma_f32_16x16x32_bf16(ah0, bh0, acc, 0, 0, 0);
        acc = __builtin_amdgcn_mfma_f32_16x16x32_bf16(ah1, bh1, acc, 0, 0, 0);
        const int rb = tile * 16 + q * 4;
        if (rb + 0 < 500) mx0 = fmaxf(mx0, acc[0]);
        if (rb + 1 < 500) mx1 = fmaxf(mx1, acc[1]);
        if (rb + 2 < 500) mx2 = fmaxf(mx2, acc[2]);
        if (rb + 3 < 500) mx3 = fmaxf(mx3, acc[3]);
    }
    float m = fmaxf(fmaxf(mx0, mx1), fmaxf(mx2, mx3));
    m = fmaxf(m, __shfl_xor(m, 16));
    m = fmaxf(m, __shfl_xor(m, 32));
    if (lane < 16) red[wave * 16 + lane] = m;
    __syncthreads();
    if (tid < 16) {
        const float mm = fmaxf(fmaxf(red[tid], red[16 + tid]), fmaxf(red[32 + tid], red[48 + tid]));
        h0[node * HID + tid] = fmaxf(mm + b2[tid], 0.f);
    }
}

// ---------------- K2: parallel scan -> rowptr, fill, dinv --------------------
__global__ __launch_bounds__(1024) void scan_kernel(
    const int* __restrict__ degi, int* __restrict__ rowptr,
    int* __restrict__ fill, float* __restrict__ dinv)
{
    __shared__ int waveTot[16];
    const int tid = threadIdx.x;
    const int lane = tid & 63;
    const int wid = tid >> 6;
    const int lo = tid * 30;
    const int hi = (lo + 30 < N_NODES) ? lo + 30 : N_NODES;
    int s = 0;
    for (int i = lo; i < hi; ++i) s += degi[i];
    int xinc = s;
#pragma unroll
    for (int off = 1; off < 64; off <<= 1) {
        const int y = __shfl_up(xinc, off);
        if (lane >= off) xinc += y;
    }
    if (lane == 63) waveTot[wid] = xinc;
    __syncthreads();
    if (tid == 0) {
        int run = 0;
#pragma unroll
        for (int w = 0; w < 16; w++) { const int t = waveTot[w]; waveTot[w] = run; run += t; }
        rowptr[N_NODES] = run;
    }
    __syncthreads();
    int run = waveTot[wid] + xinc - s;
    for (int i = lo; i < hi; ++i) {
        const int d = degi[i];
        rowptr[i] = run;
        fill[i]   = run;
        dinv[i]   = rsqrtf((float)(d + 1));
        run += d;
    }
}

// ---------------- K3: bucket CSR build + h0 prescale (fused) -----------------
__global__ void bucket_pre(const int* __restrict__ src, const int* __restrict__ dst,
                           int* __restrict__ fill, int* __restrict__ srcb,
                           const float* __restrict__ h0, const float* __restrict__ dinv,
                           float* __restrict__ h0p)
{
    const int tid = threadIdx.x;
    if (blockIdx.x < NEDGE / 256) {
        const int e = blockIdx.x * 256 + tid;
        const int d = dst[e];
        const int pos = atomicAdd(&fill[d], 1);
        srcb[pos] = src[e];
    } else {
        const int gid = (blockIdx.x - NEDGE / 256) * 256 + tid;
        h0p[gid] = h0[gid] * dinv[gid >> 4];
    }
}

// ---------------- K4: gather1: agg(h0p) -> W1+relu -> W2 -> t2p4 -------------
// 16 lanes/node = 4 edge-offsets x 4 channel-quads; float4 loads.
__global__ __launch_bounds__(256) void gather1(
    const int* __restrict__ rowptr, const int* __restrict__ srcb,
    const float* __restrict__ h0p, const float* __restrict__ dinv,
    const float* __restrict__ W1, const float* __restrict__ b1g,
    const float* __restrict__ W2, float* __restrict__ t2p4)
{
    __shared__ float w1s[256];
    __shared__ float w2s[48];
    __shared__ float b1s[16];
    const int tid = threadIdx.x;
    w1s[tid] = W1[tid];
    if (tid < 48) w2s[tid] = W2[tid];
    if (tid < 16) b1s[tid] = b1g[tid];
    __syncthreads();

    const int node = blockIdx.x * 16 + (tid >> 4);
    const int sub  = tid & 15;
    const int e4   = sub >> 2;
    const int l    = sub & 3;
    const int wl   = tid & 63;
    const int beg = rowptr[node], end = rowptr[node + 1];

    f32x4 acc = {0.f, 0.f, 0.f, 0.f};
    if (e4 == 0) acc = *(const f32x4*)(h0p + node * HID + l * 4);   // self term
    for (int i = beg + e4; i < end; i += 4) {
        const int s = srcb[i];
        const f32x4 v = *(const f32x4*)(h0p + s * HID + l * 4);
        acc += v;
    }
    // reduce over edge-offset groups (lanes xor 4, 8)
#pragma unroll
    for (int c = 0; c < 4; c++) {
        acc[c] += __shfl_xor(acc[c], 4);
        acc[c] += __shfl_xor(acc[c], 8);
    }
    // transpose via shfl: o = sub; y_o = sum_i agg[i] * W1[i][o]
    const int base = wl & ~3;
    float y = 0.f;
#pragma unroll
    for (int i = 0; i < 16; i++) {
        const float a = __shfl(acc[i & 3], base | (i >> 2));
        y = fmaf(a, w1s[i * 16 + sub], y);
    }
    const float dv = dinv[node];
    const float h = fmaxf(b1s[sub] + dv * y, 0.f);
    float d0 = h * w2s[sub * 3 + 0];
    float d1 = h * w2s[sub * 3 + 1];
    float d2 = h * w2s[sub * 3 + 2];
#pragma unroll
    for (int msk = 1; msk < 16; msk <<= 1) {
        d0 += __shfl_xor(d0, msk);
        d1 += __shfl_xor(d1, msk);
        d2 += __shfl_xor(d2, msk);
    }
    if (sub < 3) {
        const float dval = (sub == 0) ? d0 : (sub == 1) ? d1 : d2;
        t2p4[node * 4 + sub] = dval * dv;
    }
}

// ---------------- K5: gather2 + bias + log_softmax ---------------------------
// 4 edge-strided lanes/node; t2p4 padded to float4 stride.
__global__ __launch_bounds__(256) void gather2(
    const int* __restrict__ rowptr, const int* __restrict__ srcb,
    const float* __restrict__ t2p4, const float* __restrict__ dinv,
    const float* __restrict__ b2g, float* __restrict__ out)
{
    const int tid  = threadIdx.x;
    const int node = blockIdx.x * 64 + (tid >> 2);
    if (node >= N_NODES) return;
    const int l = tid & 3;
    const int beg = rowptr[node], end = rowptr[node + 1];
    f32x4 acc = {0.f, 0.f, 0.f, 0.f};
    if (l == 0) acc = *(const f32x4*)(t2p4 + node * 4);   // self term
    for (int i = beg + l; i < end; i += 4) {
        const int s = srcb[i];
        acc += *(const f32x4*)(t2p4 + s * 4);
    }
#pragma unroll
    for (int c = 0; c < 3; c++) {
        acc[c] += __shfl_xor(acc[c], 1);
        acc[c] += __shfl_xor(acc[c], 2);
    }
    const float dv = dinv[node];
    const float z0 = b2g[0] + dv * acc[0];
    const float z1 = b2g[1] + dv * acc[1];
    const float z2 = b2g[2] + dv * acc[2];
    const float m = fmaxf(z0, fmaxf(z1, z2));
    const float lg = m + logf(expf(z0 - m) + expf(z1 - m) + expf(z2 - m));
    if (l < 3) {
        const float z = (l == 0) ? z0 : (l == 1) ? z1 : z2;
        out[node * 3 + l] = z - lg;
    }
}

extern "C" void kernel_launch(void* const* d_in, const int* in_sizes, int n_in,
                              void* d_out, int out_size, void* d_ws, size_t ws_size,
                              hipStream_t stream)
{
    const float* x   = (const float*)d_in[0];
    const float* w1  = (const float*)d_in[1];
    const float* b1  = (const float*)d_in[2];
    const float* w2  = (const float*)d_in[3];
    const float* b2  = (const float*)d_in[4];
    const float* g1w = (const float*)d_in[5];
    const float* g1b = (const float*)d_in[6];
    const float* g2w = (const float*)d_in[7];
    const float* g2b = (const float*)d_in[8];
    const int*   ei  = (const int*)d_in[9];
    const int* src = ei;
    const int* dst = ei + NEDGE;

    float* ws     = (float*)d_ws;
    float* h0     = ws;                        // 480000 f (dead after bucket_pre)
    float* t2p4   = ws;                        // 120000 f (aliases dead h0)
    float* h0p    = ws + 480000;               // 480000 f
    float* dinv   = ws + 960000;               // 30000 f
    int*   rowptr = (int*)(ws + 990000);       // 30001 i (+pad)
    int*   fill   = (int*)(ws + 1020004);      // 30000 i
    int*   degi   = (int*)(ws + 1050004);      // 30000 i
    int*   srcb   = (int*)(ws + 1080004);      // 960000 i
    short* bfragsG= (short*)(ws + 2040004);    // 1024 s
    float* out    = (float*)d_out;

    setup_kernel<<<120, 256, 0, stream>>>(w2, bfragsG, degi);
    conv_fused<<<N_NODES, 256, 0, stream>>>(x, w1, b1, b2, bfragsG, dst, degi, h0);
    scan_kernel<<<1, 1024, 0, stream>>>(degi, rowptr, fill, dinv);
    bucket_pre<<<NEDGE / 256 + (N_NODES * HID) / 256, 256, 0, stream>>>(
        src, dst, fill, srcb, h0, dinv, h0p);
    gather1<<<N_NODES / 16, 256, 0, stream>>>(rowptr, srcb, h0p, dinv, g1w, g1b, g2w, t2p4);
    gather2<<<(N_NODES + 63) / 64, 256, 0, stream>>>(rowptr, srcb, t2p4, dinv, g2b, out);
}